// Round 5
// baseline (1814.915 us; speedup 1.0000x reference)
//
#include <hip/hip_runtime.h>

#define NHD 32
#define SS  2048
#define HH  4096
#define H3  12288
#define HD  128

typedef __attribute__((ext_vector_type(4))) float f32x4;
typedef __attribute__((ext_vector_type(8))) short short8;

#define GLOAD_LDS16(gptr, lptr)                                                        \
  __builtin_amdgcn_global_load_lds((const __attribute__((address_space(1))) void*)(gptr), \
                                   (__attribute__((address_space(3))) void*)(lptr), 16, 0, 0)

__device__ __forceinline__ ushort f2bf(float f) {
  union { float f; unsigned u; } v; v.f = f;
  unsigned r = (v.u + 0x7FFFu + ((v.u >> 16) & 1u)) >> 16;
  return (ushort)r;
}
__device__ __forceinline__ float bf2f(ushort u) {
  union { unsigned u; float f; } v; v.u = ((unsigned)u) << 16;
  return v.f;
}

// ---------- fp32 -> bf16 convert ----------
__global__ __launch_bounds__(256) void cvt_f32_bf16(const float* __restrict__ in,
                                                    ushort* __restrict__ out) {
  size_t i = ((size_t)blockIdx.x * 256 + threadIdx.x) * 4;
  float4 v = *(const float4*)(in + i);
  ushort4 r; r.x = f2bf(v.x); r.y = f2bf(v.y); r.z = f2bf(v.z); r.w = f2bf(v.w);
  *(ushort4*)(out + i) = r;
}

// ---------- transpose + convert: fp32 [rows][cols] -> bf16 [cols][rows] ----------
__global__ __launch_bounds__(256) void transpose_cvt(const float* __restrict__ in,
                                                     ushort* __restrict__ out,
                                                     int rows, int cols) {
  __shared__ float tile[32][33];
  int c0 = blockIdx.x * 32, r0 = blockIdx.y * 32;
  int tx = threadIdx.x, ty = threadIdx.y;
  #pragma unroll
  for (int i = ty; i < 32; i += 8)
    tile[i][tx] = in[(size_t)(r0 + i) * cols + (c0 + tx)];
  __syncthreads();
  #pragma unroll
  for (int i = ty; i < 32; i += 8)
    out[(size_t)(c0 + i) * rows + (r0 + tx)] = f2bf(tile[tx][i]);
}

// ---------- V transpose: qkvb v-part [b,s][h*128+d] -> vt [bh][d][s] (bf16) ----------
__global__ __launch_bounds__(256) void vtrans(const ushort* __restrict__ qkvb,
                                              ushort* __restrict__ vt) {
  __shared__ ushort tile[32][33];
  int s0 = blockIdx.x * 32, d0 = blockIdx.y * 32, bh = blockIdx.z;
  int b = bh >> 5, h = bh & 31;
  int tx = threadIdx.x, ty = threadIdx.y;
  #pragma unroll
  for (int i = ty; i < 32; i += 8)
    tile[i][tx] = qkvb[(size_t)(b * SS + s0 + i) * H3 + 8192 + h * 128 + d0 + tx];
  __syncthreads();
  #pragma unroll
  for (int i = ty; i < 32; i += 8)
    vt[((size_t)bh * HD + d0 + i) * SS + s0 + tx] = tile[tx][i];
}

// ---------- 256x256 8-phase bf16 GEMM (T2+T3+T4+T5): C = A[M][K] * BT[N][K]^T (+bias) ----
// 512 thr = 8 waves (2 wm x 4 wn). BK=64, double-buffered 128KiB LDS.
// Per wave: 128x64 output = 8x4 frags of 16x16x32. Per K-tile: 4 phases (C-quadrants),
// each {ds_reads | stage 1 half-tile | barrier | lgkmcnt(0) | 16 MFMA | barrier}.
// Staging: ph1->(t+1).A1, ph2->(t+1).B1, ph3->(t+2).B0, ph4->(t+2).A0; vmcnt(4)/tile.
// LDS XOR-swizzle (row&7)<<4 via pre-swizzled global source (linear gload_lds dest).
template<bool BIAS, bool OUTBF16>
__global__ __launch_bounds__(512, 2) void gemm256(const ushort* __restrict__ A,
                                                  const ushort* __restrict__ BT,
                                                  const float* __restrict__ bias,
                                                  void* __restrict__ Cv,
                                                  int N, int K) {
  __shared__ __align__(16) ushort As_[2][256 * 64];
  __shared__ __align__(16) ushort Bs_[2][256 * 64];
  const int tid = threadIdx.x;
  const int wave = tid >> 6, lane = tid & 63;
  const int g = lane >> 4, q = lane & 15;
  const int wm = wave >> 2, wn = wave & 3;
  const int m0 = blockIdx.y * 256, n0 = blockIdx.x * 256;
  const int NT = K >> 6;

  // staging geometry: half-tile = 128 rows x 64 cols; 1024 granules of 16B; 2/thread
  int srow[2], scol[2], sbase[2];
  #pragma unroll
  for (int r = 0; r < 2; ++r) {
    int gi = r * 512 + tid;
    int row = gi >> 3, colb = (gi & 7) << 4;
    srow[r] = row;
    scol[r] = (colb ^ ((row & 7) << 4)) >> 1;  // inverse-swizzled source col (elems)
    sbase[r] = (r * 512 + wave * 64) * 8;      // wave-uniform linear LDS base (elems)
  }

#define STG_A(p, h, t)                                                                   \
  do {                                                                                   \
    GLOAD_LDS16(A + (size_t)(m0 + (h) * 128 + srow[0]) * K + (t) * 64 + scol[0],         \
                &As_[p][(h) * 8192 + sbase[0]]);                                         \
    GLOAD_LDS16(A + (size_t)(m0 + (h) * 128 + srow[1]) * K + (t) * 64 + scol[1],         \
                &As_[p][(h) * 8192 + sbase[1]]);                                         \
  } while (0)
#define STG_B(p, h, t)                                                                   \
  do {                                                                                   \
    GLOAD_LDS16(BT + (size_t)(n0 + (h) * 128 + srow[0]) * K + (t) * 64 + scol[0],        \
                &Bs_[p][(h) * 8192 + sbase[0]]);                                         \
    GLOAD_LDS16(BT + (size_t)(n0 + (h) * 128 + srow[1]) * K + (t) * 64 + scol[1],        \
                &Bs_[p][(h) * 8192 + sbase[1]]);                                         \
  } while (0)

  // swizzled frag column offsets (elements), kk in {0,1} (k = kk*32 + 8g)
  int fcol[2];
  #pragma unroll
  for (int kk = 0; kk < 2; ++kk)
    fcol[kk] = ((kk * 64 + 16 * g) ^ ((q & 7) << 4)) >> 1;

  f32x4 acc[8][4] = {};
  short8 af[4][2], bf[2][2][2];

  // ---- prologue: tile0 all 4 halves + tile1 {A0,B0}; counted wait ----
  STG_A(0, 0, 0); STG_A(0, 1, 0); STG_B(0, 0, 0); STG_B(0, 1, 0);
  if (NT > 1) {
    STG_A(1, 0, 1); STG_B(1, 0, 1);
    asm volatile("s_waitcnt vmcnt(4)" ::: "memory");
  } else {
    asm volatile("s_waitcnt vmcnt(0)" ::: "memory");
  }
  __builtin_amdgcn_sched_barrier(0);
  __syncthreads();

  for (int t = 0; t < NT; ++t) {
    const int p = t & 1;
    const ushort* Ap = As_[p];
    const ushort* Bp = Bs_[p];

    // ---- phase 1: quadrant (mh=0, nh=0); stage (t+1).A1 ----
    #pragma unroll
    for (int i = 0; i < 4; ++i) {
      int row = wm * 128 + i * 16 + q;
      af[i][0] = *(const short8*)(&Ap[row * 64 + fcol[0]]);
      af[i][1] = *(const short8*)(&Ap[row * 64 + fcol[1]]);
    }
    #pragma unroll
    for (int j = 0; j < 2; ++j) {
      int row = wn * 64 + j * 16 + q;
      bf[0][j][0] = *(const short8*)(&Bp[row * 64 + fcol[0]]);
      bf[0][j][1] = *(const short8*)(&Bp[row * 64 + fcol[1]]);
    }
    if (t + 1 < NT) STG_A(p ^ 1, 1, t + 1);
    __syncthreads();
    asm volatile("s_waitcnt lgkmcnt(0)" ::: "memory");
    __builtin_amdgcn_sched_barrier(0);
    __builtin_amdgcn_s_setprio(1);
    #pragma unroll
    for (int i = 0; i < 4; ++i)
      #pragma unroll
      for (int j = 0; j < 2; ++j) {
        acc[i][j] = __builtin_amdgcn_mfma_f32_16x16x32_bf16(af[i][0], bf[0][j][0], acc[i][j], 0, 0, 0);
        acc[i][j] = __builtin_amdgcn_mfma_f32_16x16x32_bf16(af[i][1], bf[0][j][1], acc[i][j], 0, 0, 0);
      }
    __builtin_amdgcn_s_setprio(0);
    __syncthreads();

    // ---- phase 2: quadrant (mh=0, nh=1); stage (t+1).B1 ----
    #pragma unroll
    for (int j = 0; j < 2; ++j) {
      int row = wn * 64 + (2 + j) * 16 + q;
      bf[1][j][0] = *(const short8*)(&Bp[row * 64 + fcol[0]]);
      bf[1][j][1] = *(const short8*)(&Bp[row * 64 + fcol[1]]);
    }
    if (t + 1 < NT) STG_B(p ^ 1, 1, t + 1);
    __syncthreads();
    asm volatile("s_waitcnt lgkmcnt(0)" ::: "memory");
    __builtin_amdgcn_sched_barrier(0);
    __builtin_amdgcn_s_setprio(1);
    #pragma unroll
    for (int i = 0; i < 4; ++i)
      #pragma unroll
      for (int j = 0; j < 2; ++j) {
        acc[i][2 + j] = __builtin_amdgcn_mfma_f32_16x16x32_bf16(af[i][0], bf[1][j][0], acc[i][2 + j], 0, 0, 0);
        acc[i][2 + j] = __builtin_amdgcn_mfma_f32_16x16x32_bf16(af[i][1], bf[1][j][1], acc[i][2 + j], 0, 0, 0);
      }
    __builtin_amdgcn_s_setprio(0);
    __syncthreads();

    // ---- phase 3: quadrant (mh=1, nh=0); stage (t+2).B0 ----
    #pragma unroll
    for (int i = 0; i < 4; ++i) {
      int row = wm * 128 + 64 + i * 16 + q;
      af[i][0] = *(const short8*)(&Ap[row * 64 + fcol[0]]);
      af[i][1] = *(const short8*)(&Ap[row * 64 + fcol[1]]);
    }
    if (t + 2 < NT) STG_B(p, 0, t + 2);
    __syncthreads();
    asm volatile("s_waitcnt lgkmcnt(0)" ::: "memory");
    __builtin_amdgcn_sched_barrier(0);
    __builtin_amdgcn_s_setprio(1);
    #pragma unroll
    for (int i = 0; i < 4; ++i)
      #pragma unroll
      for (int j = 0; j < 2; ++j) {
        acc[4 + i][j] = __builtin_amdgcn_mfma_f32_16x16x32_bf16(af[i][0], bf[0][j][0], acc[4 + i][j], 0, 0, 0);
        acc[4 + i][j] = __builtin_amdgcn_mfma_f32_16x16x32_bf16(af[i][1], bf[0][j][1], acc[4 + i][j], 0, 0, 0);
      }
    __builtin_amdgcn_s_setprio(0);
    __syncthreads();

    // ---- phase 4: quadrant (mh=1, nh=1); stage (t+2).A0; counted vmcnt ----
    if (t + 2 < NT) STG_A(p, 0, t + 2);
    __syncthreads();
    __builtin_amdgcn_s_setprio(1);
    #pragma unroll
    for (int i = 0; i < 4; ++i)
      #pragma unroll
      for (int j = 0; j < 2; ++j) {
        acc[4 + i][2 + j] = __builtin_amdgcn_mfma_f32_16x16x32_bf16(af[i][0], bf[1][j][0], acc[4 + i][2 + j], 0, 0, 0);
        acc[4 + i][2 + j] = __builtin_amdgcn_mfma_f32_16x16x32_bf16(af[i][1], bf[1][j][1], acc[4 + i][2 + j], 0, 0, 0);
      }
    __builtin_amdgcn_s_setprio(0);
    if (t + 1 < NT) {
      if (t + 2 < NT) asm volatile("s_waitcnt vmcnt(4)" ::: "memory");
      else            asm volatile("s_waitcnt vmcnt(0)" ::: "memory");
      __builtin_amdgcn_sched_barrier(0);
    }
    __syncthreads();
  }
#undef STG_A
#undef STG_B

  // ---- epilogue: C write ----
  #pragma unroll
  for (int mf = 0; mf < 8; ++mf) {
    #pragma unroll
    for (int nf = 0; nf < 4; ++nf) {
      int gcol = n0 + wn * 64 + nf * 16 + q;
      float bv = 0.f;
      if (BIAS) bv = bias[gcol];
      #pragma unroll
      for (int r = 0; r < 4; ++r) {
        int grow = m0 + wm * 128 + mf * 16 + g * 4 + r;  // C/D: col=l&15, row=(l>>4)*4+reg
        float v = acc[mf][nf][r] + bv;
        if (OUTBF16) ((ushort*)Cv)[(size_t)grow * N + gcol] = f2bf(v);
        else         ((float*) Cv)[(size_t)grow * N + gcol] = v;
      }
    }
  }
}

// ---------- RoPE (NeoX) q,k only -> head-major [bh][s][d] bf16 ----------
__global__ __launch_bounds__(256) void rope_split(const ushort* __restrict__ qkv,
                                                  const int* __restrict__ positions,
                                                  ushort* __restrict__ qb,
                                                  ushort* __restrict__ kb) {
  int id = blockIdx.x * 256 + threadIdx.x;  // (t, h, d): t*2048 + h*64 + d
  int d = id & 63;
  int h = (id >> 6) & 31;
  int t = id >> 11;
  int b = t >> 11, s = t & 2047;
  float pos = (float)positions[t];
  float ang = pos * __expf(-(float)d * 0.14391156831212787f);
  float sv, cv;
  sincosf(ang, &sv, &cv);
  size_t src = (size_t)t * H3 + h * 128 + d;
  float q1 = bf2f(qkv[src]),        q2 = bf2f(qkv[src + 64]);
  float k1 = bf2f(qkv[src + 4096]), k2 = bf2f(qkv[src + 4160]);
  size_t dst = ((size_t)(b * NHD + h) * SS + s) * HD + d;
  qb[dst]      = f2bf(q1 * cv - q2 * sv);
  qb[dst + 64] = f2bf(q2 * cv + q1 * sv);
  kb[dst]      = f2bf(k1 * cv - k2 * sv);
  kb[dst + 64] = f2bf(k2 * cv + k1 * sv);
}

// ---------- causal flash attention (round-4 verified) ----------
__global__ __launch_bounds__(256) void attn_fwd(const ushort* __restrict__ qb,
                                                const ushort* __restrict__ kb,
                                                const ushort* __restrict__ vt,
                                                ushort* __restrict__ aout) {
  __shared__ __align__(16) ushort Ks[64 * 128];
  __shared__ __align__(16) ushort Vs[128 * 64];
  __shared__ __align__(16) ushort Pw[4 * 32 * 68];
  const float SCALE = 0.08838834764831845f;
  int tid = threadIdx.x, wave = tid >> 6, lane = tid & 63;
  int g = lane >> 4, q = lane & 15;
  int swk = (q & 7) << 4;
  int bh = blockIdx.y;
  int qb0 = blockIdx.x * 128;
  const ushort* Qh = qb + (size_t)bh * SS * HD;
  const ushort* Kh = kb + (size_t)bh * SS * HD;
  const ushort* Vh = vt + (size_t)bh * SS * HD;
  ushort* Pm = &Pw[wave * 32 * 68];

  short8 qf[2][4];
  #pragma unroll
  for (int m = 0; m < 2; ++m)
    #pragma unroll
    for (int c = 0; c < 4; ++c)
      qf[m][c] = *(const short8*)(Qh + (size_t)(qb0 + wave * 32 + m * 16 + q) * HD + c * 32 + 8 * g);

  f32x4 o[2][8] = {};
  float mrow[2][4], lrow[2][4];
  #pragma unroll
  for (int m = 0; m < 2; ++m)
    #pragma unroll
    for (int r = 0; r < 4; ++r) { mrow[m][r] = -1e30f; lrow[m][r] = 0.f; }

  int nt = (qb0 >> 6) + 2;
  for (int kt = 0; kt < nt; ++kt) {
    int kv0 = kt * 64;
    __syncthreads();
    #pragma unroll
    for (int r = 0; r < 4; ++r) {
      int gi  = r * 256 + tid;
      int row = gi >> 4, xb = (gi & 15) << 4;
      int src = xb ^ ((row & 7) << 4);
      GLOAD_LDS16(Kh + (size_t)(kv0 + row) * HD + (src >> 1),
                  &Ks[(r * 256 + wave * 64) * 8]);
    }
    #pragma unroll
    for (int r = 0; r < 4; ++r) {
      int gi  = r * 256 + tid;
      int row = gi >> 3, xb = (gi & 7) << 4;
      int src = xb ^ ((row & 7) << 4);
      GLOAD_LDS16(Vh + (size_t)row * SS + kv0 + (src >> 1),
                  &Vs[(r * 256 + wave * 64) * 8]);
    }
    __syncthreads();

    f32x4 sf[2][4] = {};
    #pragma unroll
    for (int c = 0; c < 4; ++c) {
      #pragma unroll
      for (int n = 0; n < 4; ++n) {
        int row = n * 16 + q;
        short8 kf = *(const short8*)(&Ks[row * 128 + (((c * 64 + 16 * g) ^ swk) >> 1)]);
        #pragma unroll
        for (int m = 0; m < 2; ++m)
          sf[m][n] = __builtin_amdgcn_mfma_f32_16x16x32_bf16(qf[m][c], kf, sf[m][n], 0, 0, 0);
      }
    }

    bool masked = (kt >= nt - 2);
    float corr[2][4];
    #pragma unroll
    for (int m = 0; m < 2; ++m) {
      #pragma unroll
      for (int r = 0; r < 4; ++r) {
        int qrow = qb0 + wave * 32 + m * 16 + g * 4 + r;
        float x[4];
        #pragma unroll
        for (int n = 0; n < 4; ++n) {
          x[n] = sf[m][n][r] * SCALE;
          if (masked && (kv0 + n * 16 + q > qrow)) x[n] = -1e30f;
        }
        float mx = fmaxf(fmaxf(x[0], x[1]), fmaxf(x[2], x[3]));
        #pragma unroll
        for (int off = 8; off; off >>= 1) mx = fmaxf(mx, __shfl_xor(mx, off));
        float mnew = fmaxf(mrow[m][r], mx);
        corr[m][r] = __expf(mrow[m][r] - mnew);
        mrow[m][r] = mnew;
        float rs = 0.f;
        #pragma unroll
        for (int n = 0; n < 4; ++n) {
          float p = __expf(x[n] - mnew);
          rs += p;
          Pm[(m * 16 + g * 4 + r) * 68 + n * 16 + q] = f2bf(p);
        }
        #pragma unroll
        for (int off = 8; off; off >>= 1) rs += __shfl_xor(rs, off);
        lrow[m][r] = lrow[m][r] * corr[m][r] + rs;
      }
    }
    #pragma unroll
    for (int m = 0; m < 2; ++m)
      #pragma unroll
      for (int d0 = 0; d0 < 8; ++d0)
        #pragma unroll
        for (int r = 0; r < 4; ++r) o[m][d0][r] *= corr[m][r];

    short8 pf[2][2];
    #pragma unroll
    for (int m = 0; m < 2; ++m)
      #pragma unroll
      for (int c2 = 0; c2 < 2; ++c2)
        pf[m][c2] = *(const short8*)(&Pm[(m * 16 + q) * 68 + c2 * 32 + 8 * g]);
    #pragma unroll
    for (int d0 = 0; d0 < 8; ++d0) {
      int vrow = d0 * 16 + q;
      short8 vf0 = *(const short8*)(&Vs[vrow * 64 + (((16 * g) ^ swk) >> 1)]);
      short8 vf1 = *(const short8*)(&Vs[vrow * 64 + (((64 + 16 * g) ^ swk) >> 1)]);
      #pragma unroll
      for (int m = 0; m < 2; ++m) {
        o[m][d0] = __builtin_amdgcn_mfma_f32_16x16x32_bf16(pf[m][0], vf0, o[m][d0], 0, 0, 0);
        o[m][d0] = __builtin_amdgcn_mfma_f32_16x16x32_bf16(pf[m][1], vf1, o[m][d0], 0, 0, 0);
      }
    }
  }

  int b = bh >> 5, h = bh & 31;
  #pragma unroll
  for (int m = 0; m < 2; ++m) {
    #pragma unroll
    for (int r = 0; r < 4; ++r) {
      float inv = 1.0f / lrow[m][r];
      int srow = qb0 + wave * 32 + m * 16 + g * 4 + r;
      size_t base = ((size_t)(b * SS + srow)) * HH + h * 128;
      #pragma unroll
      for (int d0 = 0; d0 < 8; ++d0)
        aout[base + d0 * 16 + q] = f2bf(o[m][d0][r] * inv);
    }
  }
}

extern "C" void kernel_launch(void* const* d_in, const int* in_sizes, int n_in,
                              void* d_out, int out_size, void* d_ws, size_t ws_size,
                              hipStream_t stream) {
  const int*   positions = (const int*)  d_in[0];
  const float* hidden    = (const float*)d_in[1];
  const float* w_qkv     = (const float*)d_in[2];
  const float* b_qkv     = (const float*)d_in[3];
  const float* w_proj    = (const float*)d_in[4];
  float* out = (float*)d_out;

  char* ws = (char*)d_ws;
  ushort* hsb   = (ushort*)(ws);
  ushort* wqkvT = (ushort*)(ws + 0x02000000ULL);
  ushort* wpT   = (ushort*)(ws + 0x08000000ULL);
  ushort* qkvb  = (ushort*)(ws + 0x0A000000ULL);
  ushort* qbuf  = (ushort*)(ws + 0x10000000ULL);
  ushort* kbuf  = (ushort*)(ws + 0x12000000ULL);
  ushort* vtb   = (ushort*)(ws + 0x14000000ULL);
  ushort* aout  = hsb;

  cvt_f32_bf16<<<16384, 256, 0, stream>>>(hidden, hsb);
  transpose_cvt<<<dim3(384, 128), dim3(32, 8), 0, stream>>>(w_qkv, wqkvT, HH, H3);
  transpose_cvt<<<dim3(128, 128), dim3(32, 8), 0, stream>>>(w_proj, wpT, HH, HH);

  // QKV GEMM: [4096][12288], 256^2 tiles -> grid 48x16
  gemm256<true, true><<<dim3(48, 16), 512, 0, stream>>>(hsb, wqkvT, b_qkv, qkvb, H3, HH);

  rope_split<<<32768, 256, 0, stream>>>(qkvb, positions, qbuf, kbuf);
  vtrans<<<dim3(64, 4, 64), dim3(32, 8), 0, stream>>>(qkvb, vtb);

  attn_fwd<<<dim3(16, 64), 256, 0, stream>>>(qbuf, kbuf, vtb, aout);

  // proj GEMM: [4096][4096] -> grid 16x16
  gemm256<false, false><<<dim3(16, 16), 512, 0, stream>>>(aout, wpT, nullptr, out, HH, HH);
}